// Round 4
// baseline (102.768 us; speedup 1.0000x reference)
//
#include <hip/hip_runtime.h>
#include <math.h>

#define BB 2
#define LL 1024
#define DD 512
#define HH 8
#define DHD 64
#define QQ 64
#define NCC 16

typedef __attribute__((ext_vector_type(8))) short s8b;   // 8 bf16 (4 VGPRs)
typedef __attribute__((ext_vector_type(4))) float f4;    // 4 fp32 acc

__device__ __forceinline__ void gld16(const void* g, void* l) {
    __builtin_amdgcn_global_load_lds(
        (const __attribute__((address_space(1))) unsigned int*)g,
        (__attribute__((address_space(3))) unsigned int*)l, 16, 0, 0);
}

__device__ __forceinline__ void bf16split(float f, unsigned short& h, unsigned short& l) {
    unsigned u  = __float_as_uint(f);
    unsigned hb = (u + 0x7FFFu + ((u >> 16) & 1u)) & 0xFFFF0000u;   // RTNE bf16
    float fh = __uint_as_float(hb);
    float fl = f - fh;
    unsigned ul = __float_as_uint(fl);
    unsigned lb = (ul + 0x7FFFu + ((ul >> 16) & 1u)) >> 16;
    h = (unsigned short)(hb >> 16);
    l = (unsigned short)lb;
}

__device__ __forceinline__ unsigned pk2(unsigned short a, unsigned short b) {
    return (unsigned)a | ((unsigned)b << 16);
}

// ---------------------------------------------------------------------------
// Kernel 0: split x / Wa / Wb / Wc into bf16 hi/lo arrays.
// ---------------------------------------------------------------------------
__global__ __launch_bounds__(256) void convert_split(
    const float* __restrict__ x, const float* __restrict__ Wa,
    const float* __restrict__ Wb, const float* __restrict__ Wc,
    unsigned short* __restrict__ xh, unsigned short* __restrict__ xl,
    unsigned short* __restrict__ wh, unsigned short* __restrict__ wl)
{
    const int g = blockIdx.x * 256 + threadIdx.x;    // float4 index
    const float* src;
    unsigned short *dh, *dl;
    if (g < 262144) {
        const size_t off = (size_t)g * 4;
        src = x + off; dh = xh + off; dl = xl + off;
    } else {
        const size_t j = (size_t)(g - 262144) * 4;   // 0..786431
        const int wsel = (int)(j >> 18);             // 262144 elements each
        const size_t r = j & 262143;
        src = (wsel == 0 ? Wa : (wsel == 1 ? Wb : Wc)) + r;
        dh = wh + j; dl = wl + j;
    }
    const float4 v = *(const float4*)src;
    const float f[4] = {v.x, v.y, v.z, v.w};
    unsigned short h[4], l[4];
    #pragma unroll
    for (int i = 0; i < 4; ++i) bf16split(f[i], h[i], l[i]);
    *(uint2*)dh = make_uint2(pk2(h[0], h[1]), pk2(h[2], h[3]));
    *(uint2*)dl = make_uint2(pk2(l[0], l[1]), pk2(l[2], l[3]));
}

// ---------------------------------------------------------------------------
// Kernel 1: MFMA GEMM  out = x @ W^T + b  via split-bf16 (hh + hl + lh).
// ---------------------------------------------------------------------------
__global__ __launch_bounds__(256) void gemm3_mfma(
    const unsigned short* __restrict__ xh, const unsigned short* __restrict__ xl,
    const unsigned short* __restrict__ wh, const unsigned short* __restrict__ wl,
    const float* __restrict__ ba, const float* __restrict__ bb, const float* __restrict__ bc,
    float* __restrict__ logA, float* __restrict__ Bf, float* __restrict__ Cf)
{
    __shared__ unsigned char lds[16384];
    unsigned char* const l_xh = lds;
    unsigned char* const l_xl = lds + 4096;
    unsigned char* const l_wh = lds + 8192;
    unsigned char* const l_wl = lds + 12288;

    const int wsel = blockIdx.x >> 8;
    const int tile = blockIdx.x & 255;
    const int m0 = (tile >> 3) << 6;     // 32 M-tiles
    const int o0 = (tile & 7) << 6;      // 8 N-tiles
    const int t  = threadIdx.x;
    const int wv = t >> 6;               // wave 0..3
    const int ln = t & 63;
    const int l15 = ln & 15;
    const int l4  = ln >> 4;             // k-group 0..3
    const int wr = (wv >> 1) << 5;       // wave row 0/32
    const int wc = (wv & 1) << 5;        // wave col 0/32

    const unsigned short* __restrict__ whp = wh + (size_t)wsel * 262144;
    const unsigned short* __restrict__ wlp = wl + (size_t)wsel * 262144;

    const size_t gx = (size_t)(m0 + ln) * DD;
    const size_t gw = (size_t)(o0 + ln) * DD;
    const int skc = wv * 8;
    const int sofs = wv * 1024;

    f4 acc[2][2] = {};

    for (int kt = 0; kt < DD; kt += 32) {
        gld16(&xh [gx + kt + skc], l_xh + sofs);
        gld16(&xl [gx + kt + skc], l_xl + sofs);
        gld16(&whp[gw + kt + skc], l_wh + sofs);
        gld16(&wlp[gw + kt + skc], l_wl + sofs);
        __syncthreads();

        const int ka = l4 * 1024;
        const s8b ah0 = *(const s8b*)(l_xh + ka + (wr      + l15) * 16);
        const s8b ah1 = *(const s8b*)(l_xh + ka + (wr + 16 + l15) * 16);
        const s8b al0 = *(const s8b*)(l_xl + ka + (wr      + l15) * 16);
        const s8b al1 = *(const s8b*)(l_xl + ka + (wr + 16 + l15) * 16);
        const s8b bh0 = *(const s8b*)(l_wh + ka + (wc      + l15) * 16);
        const s8b bh1 = *(const s8b*)(l_wh + ka + (wc + 16 + l15) * 16);
        const s8b bl0 = *(const s8b*)(l_wl + ka + (wc      + l15) * 16);
        const s8b bl1 = *(const s8b*)(l_wl + ka + (wc + 16 + l15) * 16);

        acc[0][0] = __builtin_amdgcn_mfma_f32_16x16x32_bf16(ah0, bh0, acc[0][0], 0, 0, 0);
        acc[0][1] = __builtin_amdgcn_mfma_f32_16x16x32_bf16(ah0, bh1, acc[0][1], 0, 0, 0);
        acc[1][0] = __builtin_amdgcn_mfma_f32_16x16x32_bf16(ah1, bh0, acc[1][0], 0, 0, 0);
        acc[1][1] = __builtin_amdgcn_mfma_f32_16x16x32_bf16(ah1, bh1, acc[1][1], 0, 0, 0);
        acc[0][0] = __builtin_amdgcn_mfma_f32_16x16x32_bf16(ah0, bl0, acc[0][0], 0, 0, 0);
        acc[0][1] = __builtin_amdgcn_mfma_f32_16x16x32_bf16(ah0, bl1, acc[0][1], 0, 0, 0);
        acc[1][0] = __builtin_amdgcn_mfma_f32_16x16x32_bf16(ah1, bl0, acc[1][0], 0, 0, 0);
        acc[1][1] = __builtin_amdgcn_mfma_f32_16x16x32_bf16(ah1, bl1, acc[1][1], 0, 0, 0);
        acc[0][0] = __builtin_amdgcn_mfma_f32_16x16x32_bf16(al0, bh0, acc[0][0], 0, 0, 0);
        acc[0][1] = __builtin_amdgcn_mfma_f32_16x16x32_bf16(al0, bh1, acc[0][1], 0, 0, 0);
        acc[1][0] = __builtin_amdgcn_mfma_f32_16x16x32_bf16(al1, bh0, acc[1][0], 0, 0, 0);
        acc[1][1] = __builtin_amdgcn_mfma_f32_16x16x32_bf16(al1, bh1, acc[1][1], 0, 0, 0);
        __syncthreads();
    }

    const float* __restrict__ bias = (wsel == 0) ? ba : ((wsel == 1) ? bb : bc);
    float* __restrict__ dst = (wsel == 0) ? logA : ((wsel == 1) ? Bf : Cf);
    #pragma unroll
    for (int ns = 0; ns < 2; ++ns) {
        const int col = o0 + wc + ns * 16 + l15;
        const float bv = bias[col];
        #pragma unroll
        for (int ms = 0; ms < 2; ++ms) {
            const int rbase = m0 + wr + ms * 16 + l4 * 4;
            #pragma unroll
            for (int r = 0; r < 4; ++r) {
                float v = acc[ms][ns][r] + bv;
                if (wsel == 0)
                    v = fminf(v, 0.f) - log1pf(__expf(-fabsf(v)));  // logsigmoid
                dst[(size_t)(rbase + r) * DD + col] = v;
            }
        }
    }
}

// ---------------------------------------------------------------------------
// Kernel 2a: per-chunk sums of logA.
// ---------------------------------------------------------------------------
__global__ __launch_bounds__(256) void chunk_sums256(
    const float* __restrict__ logA, float* __restrict__ csum)
{
    __shared__ float part[4][DHD];
    const int blk = blockIdx.x;       // bh*16 + c
    const int bh = blk >> 4, c = blk & 15;
    const int b = bh >> 3, h = bh & 7;
    const int t = threadIdx.x;
    const int d = t & 63, w = t >> 6;
    const size_t base = (size_t)(b * LL + c * QQ + w * 16) * DD + h * DHD + d;
    float s = 0.f;
    #pragma unroll 4
    for (int i = 0; i < 16; ++i) s += logA[base + (size_t)i * DD];
    part[w][d] = s;
    __syncthreads();
    if (t < DHD)
        csum[(size_t)blk * DHD + t] = part[0][t] + part[1][t] + part[2][t] + part[3][t];
}

// ---------------------------------------------------------------------------
// Kernel 2b: scan. 256 thr = 4 waves x 16 rows each.
// ---------------------------------------------------------------------------
__global__ __launch_bounds__(256) void scan256(
    const float* __restrict__ logA, const float* __restrict__ Bf,
    const float* __restrict__ Cf, const float* __restrict__ csum,
    float* __restrict__ Sloc, float* __restrict__ qf, float* __restrict__ kf,
    float* __restrict__ coff)
{
    __shared__ float part[4][DHD];
    const int blk = blockIdx.x;
    const int bh = blk >> 4, c = blk & 15;
    const int b = bh >> 3, h = bh & 7;
    const int t = threadIdx.x;
    const int d = t & 63, w = t >> 6;

    const size_t gbase = (size_t)(b * LL + c * QQ + w * 16) * DD + h * DHD + d;
    float ps = 0.f;
    #pragma unroll 4
    for (int i = 0; i < 16; ++i) ps += logA[gbase + (size_t)i * DD];
    part[w][d] = ps;
    __syncthreads();

    const size_t cs0 = ((size_t)bh << 4) * DHD + d;
    float off = 0.f;
    for (int cc = 0; cc < c; ++cc) off += csum[cs0 + (size_t)cc * DHD];
    const float tot = part[0][d] + part[1][d] + part[2][d] + part[3][d];
    if (t < DHD) {
        coff[((size_t)bh * 17 + c) * DHD + t] = off;
        if (c == NCC - 1) coff[((size_t)bh * 17 + 16) * DHD + t] = off + tot;
    }

    float run = 0.f;
    for (int ww = 0; ww < 4; ++ww) if (ww < w) run += part[ww][d];

    const size_t hbase = ((size_t)bh * LL + c * QQ + w * 16) * DHD + d;
    #pragma unroll 4
    for (int i = 0; i < 16; ++i) {
        const size_t gi = gbase + (size_t)i * DD;
        const float la = logA[gi];
        const float cv = Cf[gi];
        const float bv = Bf[gi];
        qf[hbase + (size_t)i * DHD] = cv * __expf(run);       // exp(Sm1 - Eprev)
        run += la;
        Sloc[hbase + (size_t)i * DHD] = run;
        kf[hbase + (size_t)i * DHD] = bv * __expf(tot - run); // exp(E - S)
    }
}

// ---------------------------------------------------------------------------
// Kernel 3: band kernel. Block = (bh, m, ng); covers n in [4ng, 4ng+4).
//  n > m : zero-fill.  n == m : skip (diag kernel).  n < m : split-bf16 MFMA
//  of qf_m @ diag(exp(coff[m]-coff[n+1])) @ kf_n^T, dv folded in fp32 at stage.
// LDS: qh/ql/kh/kl each [8 kslots][64 rows][16 B] = 8 KB -> 32 KB total.
// ---------------------------------------------------------------------------
__global__ __launch_bounds__(256) void band_kernel(
    const float* __restrict__ qf, const float* __restrict__ kf,
    const float* __restrict__ coff, float* __restrict__ out)
{
    __shared__ unsigned char lds[32768];
    unsigned char* const l_qh = lds;
    unsigned char* const l_ql = lds + 8192;
    unsigned char* const l_kh = lds + 16384;
    unsigned char* const l_kl = lds + 24576;

    const int ng = blockIdx.x & 3;
    const int m  = (blockIdx.x >> 2) & 15;
    const int bh = blockIdx.x >> 6;

    const int t  = threadIdx.x;
    const int wv = t >> 6;
    const int ln = t & 63;
    const int l15 = ln & 15;
    const int l4  = ln >> 4;
    const int wr = (wv >> 1) << 5;
    const int wc = (wv & 1) << 5;

    // staging assignment: row = t>>2 (0..63), kc = (t&3)*16 (16 k-elems)
    const int srow = t >> 2;
    const int skc  = (t & 3) << 4;
    const int slot0 = skc >> 3;          // kslot of first 8, then slot0+1

    const size_t cb = (size_t)bh * 17 * DHD;
    // coff[m] values for this thread's k-range (loaded once)
    float cm[16];
    {
        const float4 a = *(const float4*)&coff[cb + (size_t)m * DHD + skc + 0];
        const float4 b2 = *(const float4*)&coff[cb + (size_t)m * DHD + skc + 4];
        const float4 c2 = *(const float4*)&coff[cb + (size_t)m * DHD + skc + 8];
        const float4 d2 = *(const float4*)&coff[cb + (size_t)m * DHD + skc + 12];
        cm[0]=a.x; cm[1]=a.y; cm[2]=a.z; cm[3]=a.w;
        cm[4]=b2.x; cm[5]=b2.y; cm[6]=b2.z; cm[7]=b2.w;
        cm[8]=c2.x; cm[9]=c2.y; cm[10]=c2.z; cm[11]=c2.w;
        cm[12]=d2.x; cm[13]=d2.y; cm[14]=d2.z; cm[15]=d2.w;
    }

    const bool hasOff = (4 * ng) < m;

    // stage qf_m once (hi/lo split, no scale)
    if (hasOff) {
        const size_t qb = ((size_t)bh * LL + (size_t)m * QQ + srow) * DHD + skc;
        float v[16];
        #pragma unroll
        for (int g = 0; g < 4; ++g) {
            const float4 x4 = *(const float4*)&qf[qb + g * 4];
            v[g*4+0]=x4.x; v[g*4+1]=x4.y; v[g*4+2]=x4.z; v[g*4+3]=x4.w;
        }
        unsigned short h[16], l[16];
        #pragma unroll
        for (int i = 0; i < 16; ++i) bf16split(v[i], h[i], l[i]);
        *(uint4*)(l_qh + slot0*1024 + srow*16) =
            make_uint4(pk2(h[0],h[1]), pk2(h[2],h[3]), pk2(h[4],h[5]), pk2(h[6],h[7]));
        *(uint4*)(l_qh + (slot0+1)*1024 + srow*16) =
            make_uint4(pk2(h[8],h[9]), pk2(h[10],h[11]), pk2(h[12],h[13]), pk2(h[14],h[15]));
        *(uint4*)(l_ql + slot0*1024 + srow*16) =
            make_uint4(pk2(l[0],l[1]), pk2(l[2],l[3]), pk2(l[4],l[5]), pk2(l[6],l[7]));
        *(uint4*)(l_ql + (slot0+1)*1024 + srow*16) =
            make_uint4(pk2(l[8],l[9]), pk2(l[10],l[11]), pk2(l[12],l[13]), pk2(l[14],l[15]));
    }

    const size_t outbase = ((size_t)bh * LL + (size_t)m * QQ) * LL;

    for (int n = 4 * ng; n < 4 * ng + 4; ++n) {
        if (n == m) continue;
        if (n > m) {
            // zero tile: thread writes 4 float4 at row srow, cols skc..skc+15
            const size_t ob = outbase + (size_t)srow * LL + (size_t)n * QQ + skc;
            const float4 z = make_float4(0.f, 0.f, 0.f, 0.f);
            *(float4*)&out[ob + 0] = z;
            *(float4*)&out[ob + 4] = z;
            *(float4*)&out[ob + 8] = z;
            *(float4*)&out[ob + 12] = z;
            continue;
        }
        // ---- offdiag tile: stage kf_n * dv, then MFMA ----
        __syncthreads();   // previous tile's LDS readers done
        {
            float dv[16];
            #pragma unroll
            for (int g = 0; g < 4; ++g) {
                const float4 c4 = *(const float4*)&coff[cb + (size_t)(n + 1) * DHD + skc + g * 4];
                dv[g*4+0] = __expf(cm[g*4+0] - c4.x);
                dv[g*4+1] = __expf(cm[g*4+1] - c4.y);
                dv[g*4+2] = __expf(cm[g*4+2] - c4.z);
                dv[g*4+3] = __expf(cm[g*4+3] - c4.w);
            }
            const size_t kb = ((size_t)bh * LL + (size_t)n * QQ + srow) * DHD + skc;
            float v[16];
            #pragma unroll
            for (int g = 0; g < 4; ++g) {
                const float4 x4 = *(const float4*)&kf[kb + g * 4];
                v[g*4+0]=x4.x*dv[g*4+0]; v[g*4+1]=x4.y*dv[g*4+1];
                v[g*4+2]=x4.z*dv[g*4+2]; v[g*4+3]=x4.w*dv[g*4+3];
            }
            unsigned short h[16], l[16];
            #pragma unroll
            for (int i = 0; i < 16; ++i) bf16split(v[i], h[i], l[i]);
            *(uint4*)(l_kh + slot0*1024 + srow*16) =
                make_uint4(pk2(h[0],h[1]), pk2(h[2],h[3]), pk2(h[4],h[5]), pk2(h[6],h[7]));
            *(uint4*)(l_kh + (slot0+1)*1024 + srow*16) =
                make_uint4(pk2(h[8],h[9]), pk2(h[10],h[11]), pk2(h[12],h[13]), pk2(h[14],h[15]));
            *(uint4*)(l_kl + slot0*1024 + srow*16) =
                make_uint4(pk2(l[0],l[1]), pk2(l[2],l[3]), pk2(l[4],l[5]), pk2(l[6],l[7]));
            *(uint4*)(l_kl + (slot0+1)*1024 + srow*16) =
                make_uint4(pk2(l[8],l[9]), pk2(l[10],l[11]), pk2(l[12],l[13]), pk2(l[14],l[15]));
        }
        __syncthreads();

        f4 acc[2][2] = {};
        #pragma unroll
        for (int ks = 0; ks < 2; ++ks) {
            const int ka = (ks * 4 + l4) * 1024;
            const s8b ah0 = *(const s8b*)(l_qh + ka + (wr      + l15) * 16);
            const s8b ah1 = *(const s8b*)(l_qh + ka + (wr + 16 + l15) * 16);
            const s8b al0 = *(const s8b*)(l_ql + ka + (wr      + l15) * 16);
            const s8b al1 = *(const s8b*)(l_ql + ka + (wr + 16 + l15) * 16);
            const s8b bh0 = *(const s8b*)(l_kh + ka + (wc      + l15) * 16);
            const s8b bh1 = *(const s8b*)(l_kh + ka + (wc + 16 + l15) * 16);
            const s8b bl0 = *(const s8b*)(l_kl + ka + (wc      + l15) * 16);
            const s8b bl1 = *(const s8b*)(l_kl + ka + (wc + 16 + l15) * 16);

            acc[0][0] = __builtin_amdgcn_mfma_f32_16x16x32_bf16(ah0, bh0, acc[0][0], 0, 0, 0);
            acc[0][1] = __builtin_amdgcn_mfma_f32_16x16x32_bf16(ah0, bh1, acc[0][1], 0, 0, 0);
            acc[1][0] = __builtin_amdgcn_mfma_f32_16x16x32_bf16(ah1, bh0, acc[1][0], 0, 0, 0);
            acc[1][1] = __builtin_amdgcn_mfma_f32_16x16x32_bf16(ah1, bh1, acc[1][1], 0, 0, 0);
            acc[0][0] = __builtin_amdgcn_mfma_f32_16x16x32_bf16(ah0, bl0, acc[0][0], 0, 0, 0);
            acc[0][1] = __builtin_amdgcn_mfma_f32_16x16x32_bf16(ah0, bl1, acc[0][1], 0, 0, 0);
            acc[1][0] = __builtin_amdgcn_mfma_f32_16x16x32_bf16(ah1, bl0, acc[1][0], 0, 0, 0);
            acc[1][1] = __builtin_amdgcn_mfma_f32_16x16x32_bf16(ah1, bl1, acc[1][1], 0, 0, 0);
            acc[0][0] = __builtin_amdgcn_mfma_f32_16x16x32_bf16(al0, bh0, acc[0][0], 0, 0, 0);
            acc[0][1] = __builtin_amdgcn_mfma_f32_16x16x32_bf16(al0, bh1, acc[0][1], 0, 0, 0);
            acc[1][0] = __builtin_amdgcn_mfma_f32_16x16x32_bf16(al1, bh0, acc[1][0], 0, 0, 0);
            acc[1][1] = __builtin_amdgcn_mfma_f32_16x16x32_bf16(al1, bh1, acc[1][1], 0, 0, 0);
        }

        #pragma unroll
        for (int ms = 0; ms < 2; ++ms) {
            #pragma unroll
            for (int ns = 0; ns < 2; ++ns) {
                const int row0 = wr + ms * 16 + l4 * 4;
                const int col  = (int)(n * QQ) + wc + ns * 16 + l15;
                #pragma unroll
                for (int r = 0; r < 4; ++r)
                    out[outbase + (size_t)(row0 + r) * LL + col] = acc[ms][ns][r];
            }
        }
    }
}

// ---------------------------------------------------------------------------
// Kernel 4: diagonal tiles: masked elementwise  C_q exp(Sloc_{q-1}-Sloc_k) B_k.
// ---------------------------------------------------------------------------
__global__ __launch_bounds__(256) void diag_kernel(
    const float* __restrict__ Sloc, const float* __restrict__ Bf,
    const float* __restrict__ Cf, float* __restrict__ out)
{
    __shared__ float smA[DHD][65];
    __shared__ float smB[DHD][65];
    __shared__ float smC[DHD][65];

    const int blk = blockIdx.x;      // bh*16 + m
    const int bh = blk >> 4, m = blk & 15;
    const int b = bh >> 3, h = bh & 7;
    const int t = threadIdx.x;
    const int q0 = ((t >> 4) & 15) << 2;
    const int k0 = (t & 15) << 2;
    const int r  = t >> 4;
    const int dg = (t & 15) << 2;

    const size_t ab = (size_t)(b * LL + m * QQ) * DD + h * DHD;
    const size_t sb = ((size_t)bh * LL + (size_t)m * QQ) * DHD;
    #pragma unroll
    for (int rr = 0; rr < 64; rr += 16) {
        const int row = r + rr;
        float4 cv = *(const float4*)&Cf[ab + (size_t)row * DD + dg];
        smA[dg+0][row] = cv.x; smA[dg+1][row] = cv.y; smA[dg+2][row] = cv.z; smA[dg+3][row] = cv.w;
        float4 bv = *(const float4*)&Bf[ab + (size_t)row * DD + dg];
        smB[dg+0][row] = bv.x; smB[dg+1][row] = bv.y; smB[dg+2][row] = bv.z; smB[dg+3][row] = bv.w;
        float4 sv = *(const float4*)&Sloc[sb + (size_t)row * DHD + dg];
        smC[dg+0][row] = sv.x; smC[dg+1][row] = sv.y; smC[dg+2][row] = sv.z; smC[dg+3][row] = sv.w;
    }
    __syncthreads();

    float acc[4][4] = {};
    if (q0 + 3 >= k0) {
        #pragma unroll 2
        for (int d = 0; d < DHD; ++d) {
            const float4 cq = *(const float4*)&smA[d][q0];
            const float4 bk = *(const float4*)&smB[d][k0];
            const float4 sk = *(const float4*)&smC[d][k0];
            const float cqa[4] = {cq.x, cq.y, cq.z, cq.w};
            const float bka[4] = {bk.x, bk.y, bk.z, bk.w};
            const float ska[4] = {sk.x, sk.y, sk.z, sk.w};
            float s1a[4];
            #pragma unroll
            for (int i = 0; i < 4; ++i) {
                const int qi = q0 + i;
                s1a[i] = (qi == 0) ? 0.f : smC[d][qi - 1];
            }
            #pragma unroll
            for (int i = 0; i < 4; ++i) {
                #pragma unroll
                for (int j = 0; j < 4; ++j) {
                    const int qi = q0 + i, kj = k0 + j;
                    const float wgt = (qi > kj) ? __expf(s1a[i] - ska[j])
                                                : ((qi == kj) ? 1.f : 0.f);
                    acc[i][j] += cqa[i] * wgt * bka[j];
                }
            }
        }
    }
    const size_t outrow0 = ((size_t)bh * LL + (size_t)m * QQ) * LL + (size_t)m * QQ;
    #pragma unroll
    for (int i = 0; i < 4; ++i)
        *(float4*)&out[outrow0 + (size_t)(q0 + i) * LL + k0] =
            make_float4(acc[i][0], acc[i][1], acc[i][2], acc[i][3]);
}

// ---------------------------------------------------------------------------
extern "C" void kernel_launch(void* const* d_in, const int* in_sizes, int n_in,
                              void* d_out, int out_size, void* d_ws, size_t ws_size,
                              hipStream_t stream) {
    const float* x  = (const float*)d_in[0];
    const float* Wa = (const float*)d_in[1];
    const float* ba = (const float*)d_in[2];
    const float* Wb = (const float*)d_in[3];
    const float* bb = (const float*)d_in[4];
    const float* Wc = (const float*)d_in[5];
    const float* bc = (const float*)d_in[6];
    float* out = (float*)d_out;
    float* ws  = (float*)d_ws;

    const size_t NBLD = (size_t)BB * LL * DD;   // 1,048,576 floats
    float* logA = ws;
    float* Bf   = ws + 1 * NBLD;
    float* Cf   = ws + 2 * NBLD;
    float* Sl   = ws + 3 * NBLD;
    float* qf   = ws + 4 * NBLD;
    float* kf   = ws + 5 * NBLD;
    float* coff = ws + 6 * NBLD;                        // 16*17*64 floats
    float* csum = coff + (size_t)BB * HH * 17 * DHD;    // 256*64 floats

    // bf16 split arrays live in the Sl/qf/kf region: fully consumed by
    // gemm3_mfma BEFORE scan256 overwrites that region (stream-ordered).
    unsigned short* xh  = (unsigned short*)(ws + 3 * NBLD);
    unsigned short* xl  = xh + 1048576;
    unsigned short* whp = xl + 1048576;    // 3 x 262144
    unsigned short* wlp = whp + 786432;

    convert_split<<<1792, 256, 0, stream>>>(x, Wa, Wb, Wc, xh, xl, whp, wlp);
    gemm3_mfma<<<768, 256, 0, stream>>>(xh, xl, whp, wlp, ba, bb, bc, logA, Bf, Cf);
    chunk_sums256<<<BB * HH * NCC, 256, 0, stream>>>(logA, csum);
    scan256<<<BB * HH * NCC, 256, 0, stream>>>(logA, Bf, Cf, csum, Sl, qf, kf, coff);
    band_kernel<<<BB * HH * NCC * 4, 256, 0, stream>>>(qf, kf, coff, out);
    diag_kernel<<<BB * HH * NCC, 256, 0, stream>>>(Sl, Bf, Cf, out);
}

// Round 5
// 101.592 us; speedup vs baseline: 1.0116x; 1.0116x over previous
//
#include <hip/hip_runtime.h>
#include <math.h>

#define BB 2
#define LL 1024
#define DD 512
#define HH 8
#define DHD 64
#define QQ 64
#define NCC 16

typedef __attribute__((ext_vector_type(8))) short s8b;   // 8 bf16 (4 VGPRs)
typedef __attribute__((ext_vector_type(4))) float f4;    // 4 fp32 acc

__device__ __forceinline__ void gld16(const void* g, void* l) {
    __builtin_amdgcn_global_load_lds(
        (const __attribute__((address_space(1))) unsigned int*)g,
        (__attribute__((address_space(3))) unsigned int*)l, 16, 0, 0);
}

__device__ __forceinline__ void bf16split(float f, unsigned short& h, unsigned short& l) {
    unsigned u  = __float_as_uint(f);
    unsigned hb = (u + 0x7FFFu + ((u >> 16) & 1u)) & 0xFFFF0000u;   // RTNE bf16
    float fh = __uint_as_float(hb);
    float fl = f - fh;
    unsigned ul = __float_as_uint(fl);
    unsigned lb = (ul + 0x7FFFu + ((ul >> 16) & 1u)) >> 16;
    h = (unsigned short)(hb >> 16);
    l = (unsigned short)lb;
}

__device__ __forceinline__ unsigned pk2(unsigned short a, unsigned short b) {
    return (unsigned)a | ((unsigned)b << 16);
}

// ---------------------------------------------------------------------------
// Kernel 0: split x / Wa / Wb / Wc into bf16 hi/lo arrays.
// ---------------------------------------------------------------------------
__global__ __launch_bounds__(256) void convert_split(
    const float* __restrict__ x, const float* __restrict__ Wa,
    const float* __restrict__ Wb, const float* __restrict__ Wc,
    unsigned short* __restrict__ xh, unsigned short* __restrict__ xl,
    unsigned short* __restrict__ wh, unsigned short* __restrict__ wl)
{
    const int g = blockIdx.x * 256 + threadIdx.x;    // float4 index
    const float* src;
    unsigned short *dh, *dl;
    if (g < 262144) {
        const size_t off = (size_t)g * 4;
        src = x + off; dh = xh + off; dl = xl + off;
    } else {
        const size_t j = (size_t)(g - 262144) * 4;   // 0..786431
        const int wsel = (int)(j >> 18);             // 262144 elements each
        const size_t r = j & 262143;
        src = (wsel == 0 ? Wa : (wsel == 1 ? Wb : Wc)) + r;
        dh = wh + j; dl = wl + j;
    }
    const float4 v = *(const float4*)src;
    const float f[4] = {v.x, v.y, v.z, v.w};
    unsigned short h[4], l[4];
    #pragma unroll
    for (int i = 0; i < 4; ++i) bf16split(f[i], h[i], l[i]);
    *(uint2*)dh = make_uint2(pk2(h[0], h[1]), pk2(h[2], h[3]));
    *(uint2*)dl = make_uint2(pk2(l[0], l[1]), pk2(l[2], l[3]));
}

// ---------------------------------------------------------------------------
// Kernel 1: fused 3-weight MFMA GEMM, double-buffered.
// 256 blocks = (bm 32) x (bn 8); 512 thr = 8 waves (2 rows x 4 cols).
// LDS: 2 bufs x 8 arrays(xh,xl,wh0,wl0,wh1,wl1,wh2,wl2) x 4 KB = 64 KB.
// Per iter (BK=32): each wave stages ONE array (4 gld16), computes
// 2(ms) x 1 x 3(wsel) 16x16 tiles x 3 split passes = 18 MFMA.
// blockIdx&7 == bn == XCD id -> per-XCD L2 keeps its W panel resident.
// ---------------------------------------------------------------------------
__global__ __launch_bounds__(512) void gemm3_fused(
    const unsigned short* __restrict__ xh, const unsigned short* __restrict__ xl,
    const unsigned short* __restrict__ wh, const unsigned short* __restrict__ wl,
    const float* __restrict__ ba, const float* __restrict__ bb, const float* __restrict__ bc,
    float* __restrict__ logA, float* __restrict__ Bf, float* __restrict__ Cf)
{
    __shared__ unsigned char lds[65536];

    const int bm = blockIdx.x >> 3;
    const int bn = blockIdx.x & 7;
    const int m0 = bm << 6, o0 = bn << 6;
    const int t = threadIdx.x, wv = t >> 6, ln = t & 63;
    const int l15 = ln & 15, l4 = ln >> 4;
    const int wr = (wv >> 2) << 5;      // 0 / 32
    const int wc = (wv & 3) << 4;       // 0 / 16 / 32 / 48

    // staging: wave wv owns array wv (0=xh,1=xl,2=wh0,3=wl0,4=wh1,5=wl1,6=wh2,7=wl2)
    const unsigned short* hp = (wv < 2) ? xh : wh + (size_t)((wv - 2) >> 1) * 262144;
    const unsigned short* lp = (wv < 2) ? xl : wl + (size_t)((wv - 2) >> 1) * 262144;
    const size_t grow = (size_t)(((wv < 2) ? m0 : o0) + ln) * DD;
    const unsigned short* sp = ((wv & 1) ? lp : hp) + grow;
    const int abase = wv * 4096;

    f4 acc[3][2] = {};

    auto STAGE = [&](int buf, int kt) {
        unsigned char* base = lds + buf * 32768 + abase;
        #pragma unroll
        for (int s = 0; s < 4; ++s)
            gld16(sp + kt + s * 8, base + s * 1024);
    };

    auto COMPUTE = [&](int buf) {
        const unsigned char* base = lds + buf * 32768;
        const int ka = l4 * 1024;
        const s8b ah0 = *(const s8b*)(base + 0*4096 + ka + (wr      + l15) * 16);
        const s8b ah1 = *(const s8b*)(base + 0*4096 + ka + (wr + 16 + l15) * 16);
        const s8b al0 = *(const s8b*)(base + 1*4096 + ka + (wr      + l15) * 16);
        const s8b al1 = *(const s8b*)(base + 1*4096 + ka + (wr + 16 + l15) * 16);
        #pragma unroll
        for (int s = 0; s < 3; ++s) {
            const s8b bh = *(const s8b*)(base + (2 + 2*s)*4096 + ka + (wc + l15) * 16);
            const s8b bl = *(const s8b*)(base + (3 + 2*s)*4096 + ka + (wc + l15) * 16);
            acc[s][0] = __builtin_amdgcn_mfma_f32_16x16x32_bf16(ah0, bh, acc[s][0], 0, 0, 0);
            acc[s][1] = __builtin_amdgcn_mfma_f32_16x16x32_bf16(ah1, bh, acc[s][1], 0, 0, 0);
            acc[s][0] = __builtin_amdgcn_mfma_f32_16x16x32_bf16(ah0, bl, acc[s][0], 0, 0, 0);
            acc[s][1] = __builtin_amdgcn_mfma_f32_16x16x32_bf16(ah1, bl, acc[s][1], 0, 0, 0);
            acc[s][0] = __builtin_amdgcn_mfma_f32_16x16x32_bf16(al0, bh, acc[s][0], 0, 0, 0);
            acc[s][1] = __builtin_amdgcn_mfma_f32_16x16x32_bf16(al1, bh, acc[s][1], 0, 0, 0);
        }
    };

    STAGE(0, 0);
    __syncthreads();
    int cur = 0;
    for (int it = 0; it < 16; ++it) {
        if (it < 15) STAGE(cur ^ 1, (it + 1) * 32);   // prefetch next tile
        COMPUTE(cur);                                  // consume current tile
        __syncthreads();                               // drain loads + readers
        cur ^= 1;
    }

    // epilogue: bias + (logsigmoid for wsel 0), scalar stores
    const int col = o0 + wc + l15;
    const float bva = ba[col], bvb = bb[col], bvc = bc[col];
    #pragma unroll
    for (int ms = 0; ms < 2; ++ms) {
        const int row0 = m0 + wr + ms * 16 + l4 * 4;
        #pragma unroll
        for (int r = 0; r < 4; ++r) {
            const size_t o = (size_t)(row0 + r) * DD + col;
            float va = acc[0][ms][r] + bva;
            logA[o] = fminf(va, 0.f) - log1pf(__expf(-fabsf(va)));
            Bf[o] = acc[1][ms][r] + bvb;
            Cf[o] = acc[2][ms][r] + bvc;
        }
    }
}

// ---------------------------------------------------------------------------
// Kernel 2a: per-chunk sums of logA.
// ---------------------------------------------------------------------------
__global__ __launch_bounds__(256) void chunk_sums256(
    const float* __restrict__ logA, float* __restrict__ csum)
{
    __shared__ float part[4][DHD];
    const int blk = blockIdx.x;       // bh*16 + c
    const int bh = blk >> 4, c = blk & 15;
    const int b = bh >> 3, h = bh & 7;
    const int t = threadIdx.x;
    const int d = t & 63, w = t >> 6;
    const size_t base = (size_t)(b * LL + c * QQ + w * 16) * DD + h * DHD + d;
    float s = 0.f;
    #pragma unroll 4
    for (int i = 0; i < 16; ++i) s += logA[base + (size_t)i * DD];
    part[w][d] = s;
    __syncthreads();
    if (t < DHD)
        csum[(size_t)blk * DHD + t] = part[0][t] + part[1][t] + part[2][t] + part[3][t];
}

// ---------------------------------------------------------------------------
// Kernel 2b: scan. 256 thr = 4 waves x 16 rows each.
// ---------------------------------------------------------------------------
__global__ __launch_bounds__(256) void scan256(
    const float* __restrict__ logA, const float* __restrict__ Bf,
    const float* __restrict__ Cf, const float* __restrict__ csum,
    float* __restrict__ Sloc, float* __restrict__ qf, float* __restrict__ kf,
    float* __restrict__ coff)
{
    __shared__ float part[4][DHD];
    const int blk = blockIdx.x;
    const int bh = blk >> 4, c = blk & 15;
    const int b = bh >> 3, h = bh & 7;
    const int t = threadIdx.x;
    const int d = t & 63, w = t >> 6;

    const size_t gbase = (size_t)(b * LL + c * QQ + w * 16) * DD + h * DHD + d;
    float ps = 0.f;
    #pragma unroll 4
    for (int i = 0; i < 16; ++i) ps += logA[gbase + (size_t)i * DD];
    part[w][d] = ps;
    __syncthreads();

    const size_t cs0 = ((size_t)bh << 4) * DHD + d;
    float off = 0.f;
    for (int cc = 0; cc < c; ++cc) off += csum[cs0 + (size_t)cc * DHD];
    const float tot = part[0][d] + part[1][d] + part[2][d] + part[3][d];
    if (t < DHD) {
        coff[((size_t)bh * 17 + c) * DHD + t] = off;
        if (c == NCC - 1) coff[((size_t)bh * 17 + 16) * DHD + t] = off + tot;
    }

    float run = 0.f;
    for (int ww = 0; ww < 4; ++ww) if (ww < w) run += part[ww][d];

    const size_t hbase = ((size_t)bh * LL + c * QQ + w * 16) * DHD + d;
    #pragma unroll 4
    for (int i = 0; i < 16; ++i) {
        const size_t gi = gbase + (size_t)i * DD;
        const float la = logA[gi];
        const float cv = Cf[gi];
        const float bv = Bf[gi];
        qf[hbase + (size_t)i * DHD] = cv * __expf(run);       // exp(Sm1 - Eprev)
        run += la;
        Sloc[hbase + (size_t)i * DHD] = run;
        kf[hbase + (size_t)i * DHD] = bv * __expf(tot - run); // exp(E - S)
    }
}

// ---------------------------------------------------------------------------
// Kernel 3: band kernel. Block = (bh, m, ng); covers n in [4ng, 4ng+4).
//  n > m : zero-fill.  n == m : skip (diag kernel).  n < m : split-bf16 MFMA.
// ---------------------------------------------------------------------------
__global__ __launch_bounds__(256) void band_kernel(
    const float* __restrict__ qf, const float* __restrict__ kf,
    const float* __restrict__ coff, float* __restrict__ out)
{
    __shared__ unsigned char lds[32768];
    unsigned char* const l_qh = lds;
    unsigned char* const l_ql = lds + 8192;
    unsigned char* const l_kh = lds + 16384;
    unsigned char* const l_kl = lds + 24576;

    const int ng = blockIdx.x & 3;
    const int m  = (blockIdx.x >> 2) & 15;
    const int bh = blockIdx.x >> 6;

    const int t  = threadIdx.x;
    const int wv = t >> 6;
    const int ln = t & 63;
    const int l15 = ln & 15;
    const int l4  = ln >> 4;
    const int wr = (wv >> 1) << 5;
    const int wc = (wv & 1) << 5;

    const int srow = t >> 2;
    const int skc  = (t & 3) << 4;
    const int slot0 = skc >> 3;

    const size_t cb = (size_t)bh * 17 * DHD;
    float cm[16];
    {
        const float4 a = *(const float4*)&coff[cb + (size_t)m * DHD + skc + 0];
        const float4 b2 = *(const float4*)&coff[cb + (size_t)m * DHD + skc + 4];
        const float4 c2 = *(const float4*)&coff[cb + (size_t)m * DHD + skc + 8];
        const float4 d2 = *(const float4*)&coff[cb + (size_t)m * DHD + skc + 12];
        cm[0]=a.x; cm[1]=a.y; cm[2]=a.z; cm[3]=a.w;
        cm[4]=b2.x; cm[5]=b2.y; cm[6]=b2.z; cm[7]=b2.w;
        cm[8]=c2.x; cm[9]=c2.y; cm[10]=c2.z; cm[11]=c2.w;
        cm[12]=d2.x; cm[13]=d2.y; cm[14]=d2.z; cm[15]=d2.w;
    }

    const bool hasOff = (4 * ng) < m;

    if (hasOff) {
        const size_t qb = ((size_t)bh * LL + (size_t)m * QQ + srow) * DHD + skc;
        float v[16];
        #pragma unroll
        for (int g = 0; g < 4; ++g) {
            const float4 x4 = *(const float4*)&qf[qb + g * 4];
            v[g*4+0]=x4.x; v[g*4+1]=x4.y; v[g*4+2]=x4.z; v[g*4+3]=x4.w;
        }
        unsigned short h[16], l[16];
        #pragma unroll
        for (int i = 0; i < 16; ++i) bf16split(v[i], h[i], l[i]);
        *(uint4*)(l_qh + slot0*1024 + srow*16) =
            make_uint4(pk2(h[0],h[1]), pk2(h[2],h[3]), pk2(h[4],h[5]), pk2(h[6],h[7]));
        *(uint4*)(l_qh + (slot0+1)*1024 + srow*16) =
            make_uint4(pk2(h[8],h[9]), pk2(h[10],h[11]), pk2(h[12],h[13]), pk2(h[14],h[15]));
        *(uint4*)(l_ql + slot0*1024 + srow*16) =
            make_uint4(pk2(l[0],l[1]), pk2(l[2],l[3]), pk2(l[4],l[5]), pk2(l[6],l[7]));
        *(uint4*)(l_ql + (slot0+1)*1024 + srow*16) =
            make_uint4(pk2(l[8],l[9]), pk2(l[10],l[11]), pk2(l[12],l[13]), pk2(l[14],l[15]));
    }

    const size_t outbase = ((size_t)bh * LL + (size_t)m * QQ) * LL;

    for (int n = 4 * ng; n < 4 * ng + 4; ++n) {
        if (n == m) continue;
        if (n > m) {
            const size_t ob = outbase + (size_t)srow * LL + (size_t)n * QQ + skc;
            const float4 z = make_float4(0.f, 0.f, 0.f, 0.f);
            *(float4*)&out[ob + 0] = z;
            *(float4*)&out[ob + 4] = z;
            *(float4*)&out[ob + 8] = z;
            *(float4*)&out[ob + 12] = z;
            continue;
        }
        __syncthreads();
        {
            float dv[16];
            #pragma unroll
            for (int g = 0; g < 4; ++g) {
                const float4 c4 = *(const float4*)&coff[cb + (size_t)(n + 1) * DHD + skc + g * 4];
                dv[g*4+0] = __expf(cm[g*4+0] - c4.x);
                dv[g*4+1] = __expf(cm[g*4+1] - c4.y);
                dv[g*4+2] = __expf(cm[g*4+2] - c4.z);
                dv[g*4+3] = __expf(cm[g*4+3] - c4.w);
            }
            const size_t kb = ((size_t)bh * LL + (size_t)n * QQ + srow) * DHD + skc;
            float v[16];
            #pragma unroll
            for (int g = 0; g < 4; ++g) {
                const float4 x4 = *(const float4*)&kf[kb + g * 4];
                v[g*4+0]=x4.x*dv[g*4+0]; v[g*4+1]=x4.y*dv[g*4+1];
                v[g*4+2]=x4.z*dv[g*4+2]; v[g*4+3]=x4.w*dv[g*4+3];
            }
            unsigned short h[16], l[16];
            #pragma unroll
            for (int i = 0; i < 16; ++i) bf16split(v[i], h[i], l[i]);
            *(uint4*)(l_kh + slot0*1024 + srow*16) =
                make_uint4(pk2(h[0],h[1]), pk2(h[2],h[3]), pk2(h[4],h[5]), pk2(h[6],h[7]));
            *(uint4*)(l_kh + (slot0+1)*1024 + srow*16) =
                make_uint4(pk2(h[8],h[9]), pk2(h[10],h[11]), pk2(h[12],h[13]), pk2(h[14],h[15]));
            *(uint4*)(l_kl + slot0*1024 + srow*16) =
                make_uint4(pk2(l[0],l[1]), pk2(l[2],l[3]), pk2(l[4],l[5]), pk2(l[6],l[7]));
            *(uint4*)(l_kl + (slot0+1)*1024 + srow*16) =
                make_uint4(pk2(l[8],l[9]), pk2(l[10],l[11]), pk2(l[12],l[13]), pk2(l[14],l[15]));
        }
        __syncthreads();

        f4 acc[2][2] = {};
        #pragma unroll
        for (int ks = 0; ks < 2; ++ks) {
            const int ka = (ks * 4 + l4) * 1024;
            const s8b ah0 = *(const s8b*)(l_qh + ka + (wr      + l15) * 16);
            const s8b ah1 = *(const s8b*)(l_qh + ka + (wr + 16 + l15) * 16);
            const s8b al0 = *(const s8b*)(l_ql + ka + (wr      + l15) * 16);
            const s8b al1 = *(const s8b*)(l_ql + ka + (wr + 16 + l15) * 16);
            const s8b bh0 = *(const s8b*)(l_kh + ka + (wc      + l15) * 16);
            const s8b bh1 = *(const s8b*)(l_kh + ka + (wc + 16 + l15) * 16);
            const s8b bl0 = *(const s8b*)(l_kl + ka + (wc      + l15) * 16);
            const s8b bl1 = *(const s8b*)(l_kl + ka + (wc + 16 + l15) * 16);

            acc[0][0] = __builtin_amdgcn_mfma_f32_16x16x32_bf16(ah0, bh0, acc[0][0], 0, 0, 0);
            acc[0][1] = __builtin_amdgcn_mfma_f32_16x16x32_bf16(ah0, bh1, acc[0][1], 0, 0, 0);
            acc[1][0] = __builtin_amdgcn_mfma_f32_16x16x32_bf16(ah1, bh0, acc[1][0], 0, 0, 0);
            acc[1][1] = __builtin_amdgcn_mfma_f32_16x16x32_bf16(ah1, bh1, acc[1][1], 0, 0, 0);
            acc[0][0] = __builtin_amdgcn_mfma_f32_16x16x32_bf16(ah0, bl0, acc[0][0], 0, 0, 0);
            acc[0][1] = __builtin_amdgcn_mfma_f32_16x16x32_bf16(ah0, bl1, acc[0][1], 0, 0, 0);
            acc[1][0] = __builtin_amdgcn_mfma_f32_16x16x32_bf16(ah1, bl0, acc[1][0], 0, 0, 0);
            acc[1][1] = __builtin_amdgcn_mfma_f32_16x16x32_bf16(ah1, bl1, acc[1][1], 0, 0, 0);
            acc[0][0] = __builtin_amdgcn_mfma_f32_16x16x32_bf16(al0, bh0, acc[0][0], 0, 0, 0);
            acc[0][1] = __builtin_amdgcn_mfma_f32_16x16x32_bf16(al0, bh1, acc[0][1], 0, 0, 0);
            acc[1][0] = __builtin_amdgcn_mfma_f32_16x16x32_bf16(al1, bh0, acc[1][0], 0, 0, 0);
            acc[1][1] = __builtin_amdgcn_mfma_f32_16x16x32_bf16(al1, bh1, acc[1][1], 0, 0, 0);
        }

        #pragma unroll
        for (int ms = 0; ms < 2; ++ms) {
            #pragma unroll
            for (int ns = 0; ns < 2; ++ns) {
                const int row0 = wr + ms * 16 + l4 * 4;
                const int col  = (int)(n * QQ) + wc + ns * 16 + l15;
                #pragma unroll
                for (int r = 0; r < 4; ++r)
                    out[outbase + (size_t)(row0 + r) * LL + col] = acc[ms][ns][r];
            }
        }
    }
}

// ---------------------------------------------------------------------------
// Kernel 4: diagonal tiles: masked elementwise  C_q exp(Sloc_{q-1}-Sloc_k) B_k.
// ---------------------------------------------------------------------------
__global__ __launch_bounds__(256) void diag_kernel(
    const float* __restrict__ Sloc, const float* __restrict__ Bf,
    const float* __restrict__ Cf, float* __restrict__ out)
{
    __shared__ float smA[DHD][65];
    __shared__ float smB[DHD][65];
    __shared__ float smC[DHD][65];

    const int blk = blockIdx.x;      // bh*16 + m
    const int bh = blk >> 4, m = blk & 15;
    const int b = bh >> 3, h = bh & 7;
    const int t = threadIdx.x;
    const int q0 = ((t >> 4) & 15) << 2;
    const int k0 = (t & 15) << 2;
    const int r  = t >> 4;
    const int dg = (t & 15) << 2;

    const size_t ab = (size_t)(b * LL + m * QQ) * DD + h * DHD;
    const size_t sb = ((size_t)bh * LL + (size_t)m * QQ) * DHD;
    #pragma unroll
    for (int rr = 0; rr < 64; rr += 16) {
        const int row = r + rr;
        float4 cv = *(const float4*)&Cf[ab + (size_t)row * DD + dg];
        smA[dg+0][row] = cv.x; smA[dg+1][row] = cv.y; smA[dg+2][row] = cv.z; smA[dg+3][row] = cv.w;
        float4 bv = *(const float4*)&Bf[ab + (size_t)row * DD + dg];
        smB[dg+0][row] = bv.x; smB[dg+1][row] = bv.y; smB[dg+2][row] = bv.z; smB[dg+3][row] = bv.w;
        float4 sv = *(const float4*)&Sloc[sb + (size_t)row * DHD + dg];
        smC[dg+0][row] = sv.x; smC[dg+1][row] = sv.y; smC[dg+2][row] = sv.z; smC[dg+3][row] = sv.w;
    }
    __syncthreads();

    float acc[4][4] = {};
    if (q0 + 3 >= k0) {
        #pragma unroll 2
        for (int d = 0; d < DHD; ++d) {
            const float4 cq = *(const float4*)&smA[d][q0];
            const float4 bk = *(const float4*)&smB[d][k0];
            const float4 sk = *(const float4*)&smC[d][k0];
            const float cqa[4] = {cq.x, cq.y, cq.z, cq.w};
            const float bka[4] = {bk.x, bk.y, bk.z, bk.w};
            const float ska[4] = {sk.x, sk.y, sk.z, sk.w};
            float s1a[4];
            #pragma unroll
            for (int i = 0; i < 4; ++i) {
                const int qi = q0 + i;
                s1a[i] = (qi == 0) ? 0.f : smC[d][qi - 1];
            }
            #pragma unroll
            for (int i = 0; i < 4; ++i) {
                #pragma unroll
                for (int j = 0; j < 4; ++j) {
                    const int qi = q0 + i, kj = k0 + j;
                    const float wgt = (qi > kj) ? __expf(s1a[i] - ska[j])
                                                : ((qi == kj) ? 1.f : 0.f);
                    acc[i][j] += cqa[i] * wgt * bka[j];
                }
            }
        }
    }
    const size_t outrow0 = ((size_t)bh * LL + (size_t)m * QQ) * LL + (size_t)m * QQ;
    #pragma unroll
    for (int i = 0; i < 4; ++i)
        *(float4*)&out[outrow0 + (size_t)(q0 + i) * LL + k0] =
            make_float4(acc[i][0], acc[i][1], acc[i][2], acc[i][3]);
}

// ---------------------------------------------------------------------------
extern "C" void kernel_launch(void* const* d_in, const int* in_sizes, int n_in,
                              void* d_out, int out_size, void* d_ws, size_t ws_size,
                              hipStream_t stream) {
    const float* x  = (const float*)d_in[0];
    const float* Wa = (const float*)d_in[1];
    const float* ba = (const float*)d_in[2];
    const float* Wb = (const float*)d_in[3];
    const float* bb = (const float*)d_in[4];
    const float* Wc = (const float*)d_in[5];
    const float* bc = (const float*)d_in[6];
    float* out = (float*)d_out;
    float* ws  = (float*)d_ws;

    const size_t NBLD = (size_t)BB * LL * DD;   // 1,048,576 floats
    float* logA = ws;
    float* Bf   = ws + 1 * NBLD;
    float* Cf   = ws + 2 * NBLD;
    float* Sl   = ws + 3 * NBLD;
    float* qf   = ws + 4 * NBLD;
    float* kf   = ws + 5 * NBLD;
    float* coff = ws + 6 * NBLD;                        // 16*17*64 floats
    float* csum = coff + (size_t)BB * HH * 17 * DHD;    // 256*64 floats

    // bf16 split arrays live in the Sl/qf/kf region: fully consumed by
    // gemm3_fused BEFORE scan256 overwrites that region (stream-ordered).
    unsigned short* xh  = (unsigned short*)(ws + 3 * NBLD);
    unsigned short* xl  = xh + 1048576;
    unsigned short* whp = xl + 1048576;    // 3 x 262144
    unsigned short* wlp = whp + 786432;

    convert_split<<<1792, 256, 0, stream>>>(x, Wa, Wb, Wc, xh, xl, whp, wlp);
    gemm3_fused<<<256, 512, 0, stream>>>(xh, xl, whp, wlp, ba, bb, bc, logA, Bf, Cf);
    chunk_sums256<<<BB * HH * NCC, 256, 0, stream>>>(logA, csum);
    scan256<<<BB * HH * NCC, 256, 0, stream>>>(logA, Bf, Cf, csum, Sl, qf, kf, coff);
    band_kernel<<<BB * HH * NCC * 4, 256, 0, stream>>>(qf, kf, coff, out);
    diag_kernel<<<BB * HH * NCC, 256, 0, stream>>>(Sl, Bf, Cf, out);
}